// Round 1
// baseline (955.301 us; speedup 1.0000x reference)
//
#include <hip/hip_runtime.h>
#include <hip/hip_bf16.h>
#include <cstdint>

typedef __bf16 bf16x8 __attribute__((ext_vector_type(8)));
typedef float  f32x4  __attribute__((ext_vector_type(4)));
typedef unsigned short u16;
typedef u16 u16x8 __attribute__((ext_vector_type(8)));

__device__ __forceinline__ u16 f2bf(float f) {
    union { float f; uint32_t u; } x{f};
    uint32_t u = x.u;
    return (u16)((u + 0x7fffu + ((u >> 16) & 1u)) >> 16);
}

__device__ __forceinline__ float gelu_f(float x) {
    return 0.5f * x * (1.0f + erff(x * 0.70710678118654752f));
}

// async global->LDS, 16B per lane; LDS dest is wave-uniform base + lane*16
__device__ __forceinline__ void gl_lds16(const void* g, void* l) {
    __builtin_amdgcn_global_load_lds(
        (__attribute__((address_space(1))) void*)(void*)g,
        (__attribute__((address_space(3))) void*)l, 16, 0, 0);
}

#define MFMA16(a, b, c) __builtin_amdgcn_mfma_f32_16x16x32_bf16((a), (b), (c), 0, 0, 0)

// ---------------------------------------------------------------------------
// GEMM: C[M,N] = A[M,K](bf16) @ Bt[N,K]^T(bf16) + bias; EPI: 0=none 1=gelu
// OUTF32: 1 -> f32 out, 0 -> bf16 out. Tiles 128x128, BK=64, 4 waves (2x2).
// LDS tiles XOR-swizzled; swizzle applied on the global SOURCE address so the
// linear global_load_lds write lands swizzled (both-sides rule).
// ---------------------------------------------------------------------------
template<int EPI, int OUTF32>
__global__ __launch_bounds__(256, 2) void gemm_bf16(
    const u16* __restrict__ A, const u16* __restrict__ Bt,
    const float* __restrict__ bias, void* __restrict__ Cout,
    int N_, int K_)
{
    __shared__ u16 lA[128 * 64];
    __shared__ u16 lB[128 * 64];
    const int tid  = threadIdx.x;
    const int lane = tid & 63;
    const int wave = tid >> 6;
    const int wr = wave >> 1, wc = wave & 1;
    const long row0 = (long)blockIdx.y * 128;
    const long col0 = (long)blockIdx.x * 128;

    f32x4 acc[4][4];
#pragma unroll
    for (int i = 0; i < 4; ++i)
#pragma unroll
        for (int j = 0; j < 4; ++j)
#pragma unroll
            for (int t = 0; t < 4; ++t) acc[i][j][t] = 0.f;

    int sRow[4], sKb[4];
#pragma unroll
    for (int t = 0; t < 4; ++t) {
        int byteoff = (wave * 4 + t) * 1024 + lane * 16;
        int r = byteoff >> 7;                       // tile row (128B rows)
        sRow[t] = r;
        sKb[t]  = (byteoff & 127) ^ ((r & 7) << 4); // inverse-swizzled source col
    }
    const int laneRC = lane & 15;
    const int laneK2 = (lane >> 4) * 16;

    for (int k0 = 0; k0 < K_; k0 += 64) {
#pragma unroll
        for (int t = 0; t < 4; ++t) {
            const int cb = (wave * 4 + t) * 1024;
            gl_lds16(A  + (row0 + sRow[t]) * K_ + k0 + (sKb[t] >> 1), (char*)lA + cb);
            gl_lds16(Bt + (col0 + sRow[t]) * K_ + k0 + (sKb[t] >> 1), (char*)lB + cb);
        }
        __syncthreads();
#pragma unroll
        for (int kk = 0; kk < 2; ++kk) {
            bf16x8 af[4], bfr[4];
#pragma unroll
            for (int i = 0; i < 4; ++i) {
                int r = wr * 64 + i * 16 + laneRC;
                af[i] = *(const bf16x8*)((const char*)lA + r * 128 + ((kk * 64 + laneK2) ^ ((r & 7) << 4)));
            }
#pragma unroll
            for (int j = 0; j < 4; ++j) {
                int n = wc * 64 + j * 16 + laneRC;
                bfr[j] = *(const bf16x8*)((const char*)lB + n * 128 + ((kk * 64 + laneK2) ^ ((n & 7) << 4)));
            }
#pragma unroll
            for (int i = 0; i < 4; ++i)
#pragma unroll
                for (int j = 0; j < 4; ++j)
                    acc[i][j] = MFMA16(af[i], bfr[j], acc[i][j]);
        }
        __syncthreads();
    }

#pragma unroll
    for (int j = 0; j < 4; ++j) {
        const long cidx = col0 + wc * 64 + j * 16 + laneRC;
        const float bvv = bias[cidx];
#pragma unroll
        for (int i = 0; i < 4; ++i) {
            const long rbase = row0 + wr * 64 + i * 16 + ((lane >> 4) << 2);
#pragma unroll
            for (int t = 0; t < 4; ++t) {
                float v = acc[i][j][t] + bvv;
                if (EPI) v = gelu_f(v);
                const long off = (rbase + t) * N_ + cidx;
                if (OUTF32) ((float*)Cout)[off] = v;
                else        ((u16*)Cout)[off]  = f2bf(v);
            }
        }
    }
}

// ---------------------------------------------------------------------------
// Flash attention: qkv [4096][2304] bf16 (cols: q|k|v, head-major within each).
// Block = 4 waves, 128 q-rows (32/wave); KB=64; online softmax f32.
// ---------------------------------------------------------------------------
__global__ __launch_bounds__(256, 2) void attn_fwd(
    const u16* __restrict__ qkv, u16* __restrict__ outb, float scale)
{
    __shared__ u16 lQ[128 * 64];
    __shared__ u16 lK[64 * 64];
    __shared__ u16 lVt[64 * 64];
    __shared__ u16 lP[128 * 64];
    const int bh = blockIdx.x;           // b*12 + h
    const int b = bh / 12, h = bh % 12;
    const int q0 = blockIdx.y * 128;
    const int tid = threadIdx.x, lane = tid & 63, wave = tid >> 6;
    const long baseQ = (long)b * 2048 * 2304 + h * 64;
    const long baseK = baseQ + 768;
    const long baseV = baseQ + 1536;
    const int laneRC = lane & 15;
    const int laneK2 = (lane >> 4) * 16;

    // stage Q tile [128][64] (swizzled)
#pragma unroll
    for (int t = 0; t < 4; ++t) {
        const int cb = (wave * 4 + t) * 1024;
        int byteoff = cb + lane * 16;
        int r = byteoff >> 7;
        int kb = (byteoff & 127) ^ ((r & 7) << 4);
        gl_lds16(qkv + baseQ + (long)(q0 + r) * 2304 + (kb >> 1), (char*)lQ + cb);
    }
    __syncthreads();
    bf16x8 qf[2][2];
#pragma unroll
    for (int rb = 0; rb < 2; ++rb)
#pragma unroll
        for (int kk = 0; kk < 2; ++kk) {
            int r = wave * 32 + rb * 16 + laneRC;
            qf[rb][kk] = *(const bf16x8*)((const char*)lQ + r * 128 + ((kk * 64 + laneK2) ^ ((r & 7) << 4)));
        }

    float mrun[2][4], lrun[2][4];
    f32x4 oacc[2][4];
#pragma unroll
    for (int rb = 0; rb < 2; ++rb)
#pragma unroll
        for (int r = 0; r < 4; ++r) { mrun[rb][r] = -1e30f; lrun[rb][r] = 0.f; }
#pragma unroll
    for (int rb = 0; rb < 2; ++rb)
#pragma unroll
        for (int dc = 0; dc < 4; ++dc)
#pragma unroll
            for (int t = 0; t < 4; ++t) oacc[rb][dc][t] = 0.f;

    for (int kt = 0; kt < 32; ++kt) {
        __syncthreads();                 // prior PV reads of lK/lVt done
        const int kb0 = kt * 64;
#pragma unroll
        for (int t = 0; t < 2; ++t) {    // stage K tile [64][64]
            const int cb = (wave * 2 + t) * 1024;
            int byteoff = cb + lane * 16;
            int r = byteoff >> 7;
            int kb = (byteoff & 127) ^ ((r & 7) << 4);
            gl_lds16(qkv + baseK + (long)(kb0 + r) * 2304 + (kb >> 1), (char*)lK + cb);
        }
        {   // stage V transposed: thread = (key=lane, dgroup=wave)
            const int kv = lane, dg = wave;
            const u16x8* gv = (const u16x8*)(qkv + baseV + (long)(kb0 + kv) * 2304 + dg * 16);
            u16x8 v0 = gv[0], v1 = gv[1];
#pragma unroll
            for (int j = 0; j < 8; ++j) {
                int d0 = dg * 16 + j;
                *(u16*)((char*)lVt + d0 * 128 + ((kv * 2) ^ ((d0 & 7) << 4))) = v0[j];
                int d1 = dg * 16 + 8 + j;
                *(u16*)((char*)lVt + d1 * 128 + ((kv * 2) ^ ((d1 & 7) << 4))) = v1[j];
            }
        }
        __syncthreads();

        // S = Q K^T  (rows=q, cols=key)
        f32x4 s[2][4];
#pragma unroll
        for (int rb = 0; rb < 2; ++rb)
#pragma unroll
            for (int cb = 0; cb < 4; ++cb)
#pragma unroll
                for (int t = 0; t < 4; ++t) s[rb][cb][t] = 0.f;
#pragma unroll
        for (int kk = 0; kk < 2; ++kk) {
            bf16x8 kf[4];
#pragma unroll
            for (int cb = 0; cb < 4; ++cb) {
                int kr = cb * 16 + laneRC;
                kf[cb] = *(const bf16x8*)((const char*)lK + kr * 128 + ((kk * 64 + laneK2) ^ ((kr & 7) << 4)));
            }
#pragma unroll
            for (int rb = 0; rb < 2; ++rb)
#pragma unroll
                for (int cb = 0; cb < 4; ++cb)
                    s[rb][cb] = MFMA16(qf[rb][kk], kf[cb], s[rb][cb]);
        }

        // online softmax; P -> LDS (bf16, swizzled); each wave owns its rows
#pragma unroll
        for (int rb = 0; rb < 2; ++rb) {
            float tm[4];
#pragma unroll
            for (int r = 0; r < 4; ++r) {
                float v = fmaxf(fmaxf(s[rb][0][r], s[rb][1][r]),
                                fmaxf(s[rb][2][r], s[rb][3][r])) * scale;
#pragma unroll
                for (int msk = 1; msk < 16; msk <<= 1) v = fmaxf(v, __shfl_xor(v, msk, 64));
                tm[r] = v;
            }
            float corr[4], mn[4], rs[4];
#pragma unroll
            for (int r = 0; r < 4; ++r) {
                mn[r] = fmaxf(mrun[rb][r], tm[r]);
                corr[r] = __expf(mrun[rb][r] - mn[r]);
                mrun[rb][r] = mn[r];
                rs[r] = 0.f;
            }
#pragma unroll
            for (int cb2 = 0; cb2 < 4; ++cb2) {
                int pcol = cb2 * 16 + laneRC;
#pragma unroll
                for (int r = 0; r < 4; ++r) {
                    float pv = __expf(s[rb][cb2][r] * scale - mn[r]);
                    rs[r] += pv;
                    int prow = wave * 32 + rb * 16 + ((lane >> 4) << 2) + r;
                    *(u16*)((char*)lP + prow * 128 + ((pcol * 2) ^ ((prow & 7) << 4))) = f2bf(pv);
                }
            }
#pragma unroll
            for (int r = 0; r < 4; ++r) {
#pragma unroll
                for (int msk = 1; msk < 16; msk <<= 1) rs[r] += __shfl_xor(rs[r], msk, 64);
                lrun[rb][r] = lrun[rb][r] * corr[r] + rs[r];
            }
#pragma unroll
            for (int dc = 0; dc < 4; ++dc)
#pragma unroll
                for (int r = 0; r < 4; ++r) oacc[rb][dc][r] *= corr[r];
        }

        // O += P @ V
#pragma unroll
        for (int kk = 0; kk < 2; ++kk) {
            bf16x8 pf[2], vf[4];
#pragma unroll
            for (int rb = 0; rb < 2; ++rb) {
                int pr = wave * 32 + rb * 16 + laneRC;
                pf[rb] = *(const bf16x8*)((const char*)lP + pr * 128 + ((kk * 64 + laneK2) ^ ((pr & 7) << 4)));
            }
#pragma unroll
            for (int dc = 0; dc < 4; ++dc) {
                int d = dc * 16 + laneRC;
                vf[dc] = *(const bf16x8*)((const char*)lVt + d * 128 + ((kk * 64 + laneK2) ^ ((d & 7) << 4)));
            }
#pragma unroll
            for (int rb = 0; rb < 2; ++rb)
#pragma unroll
                for (int dc = 0; dc < 4; ++dc)
                    oacc[rb][dc] = MFMA16(pf[rb], vf[dc], oacc[rb][dc]);
        }
    }

#pragma unroll
    for (int rb = 0; rb < 2; ++rb)
#pragma unroll
        for (int dc = 0; dc < 4; ++dc)
#pragma unroll
            for (int r = 0; r < 4; ++r) {
                long row = (long)b * 2048 + q0 + wave * 32 + rb * 16 + ((lane >> 4) << 2) + r;
                int col = h * 64 + dc * 16 + laneRC;
                outb[row * 768 + col] = f2bf(oacc[rb][dc][r] / lrun[rb][r]);
            }
}

// ---------------------------------------------------------------------------
// fused residual-add + LayerNorm; emits f32 (optional) and bf16
// ---------------------------------------------------------------------------
__global__ __launch_bounds__(256) void ln_fused(
    const float* __restrict__ a, const float* __restrict__ bres,
    const float* __restrict__ g, const float* __restrict__ be,
    float* __restrict__ outf, u16* __restrict__ outb)
{
    const int row = blockIdx.x, tid = threadIdx.x;
    const int wave = tid >> 6, lane = tid & 63;
    const size_t rbase = (size_t)row * 768;
    float v[3]; int idx[3];
    float s1 = 0.f, s2 = 0.f;
#pragma unroll
    for (int i = 0; i < 3; ++i) {
        idx[i] = tid + i * 256;
        float x = a[rbase + idx[i]];
        if (bres) x += bres[rbase + idx[i]];
        v[i] = x; s1 += x; s2 += x * x;
    }
#pragma unroll
    for (int m = 1; m < 64; m <<= 1) { s1 += __shfl_xor(s1, m, 64); s2 += __shfl_xor(s2, m, 64); }
    __shared__ float rs1[4], rs2[4];
    if (lane == 0) { rs1[wave] = s1; rs2[wave] = s2; }
    __syncthreads();
    s1 = rs1[0] + rs1[1] + rs1[2] + rs1[3];
    s2 = rs2[0] + rs2[1] + rs2[2] + rs2[3];
    const float mean = s1 * (1.f / 768.f);
    const float var  = s2 * (1.f / 768.f) - mean * mean;
    const float rstd = rsqrtf(var + 1e-5f);
#pragma unroll
    for (int i = 0; i < 3; ++i) {
        float y = (v[i] - mean) * rstd * g[idx[i]] + be[idx[i]];
        if (outf) outf[rbase + idx[i]] = y;
        outb[rbase + idx[i]] = f2bf(y);
    }
}

// f32 [R][C] -> bf16 [C][R]
__global__ void transpose_cvt(const float* __restrict__ in, u16* __restrict__ out, int R, int C)
{
    __shared__ float t[32][33];
    const int c0 = blockIdx.x * 32, r0 = blockIdx.y * 32;
    const int tx = threadIdx.x, ty = threadIdx.y;
#pragma unroll
    for (int i = 0; i < 4; ++i)
        t[ty + 8 * i][tx] = in[(size_t)(r0 + ty + 8 * i) * C + c0 + tx];
    __syncthreads();
#pragma unroll
    for (int i = 0; i < 4; ++i)
        out[(size_t)(c0 + ty + 8 * i) * R + r0 + tx] = f2bf(t[tx][ty + 8 * i]);
}

__global__ void cvt_bf16_k(const float* __restrict__ in, u16* __restrict__ out, long n)
{
    long i = ((long)blockIdx.x * 256 + threadIdx.x) * 4;
    if (i >= n) return;
    const float4 f = *(const float4*)(in + i);
    ushort4 u; u.x = f2bf(f.x); u.y = f2bf(f.y); u.z = f2bf(f.z); u.w = f2bf(f.w);
    *(ushort4*)(out + i) = u;
}

__global__ void concat_bias(const float* __restrict__ bq, const float* __restrict__ bk,
                            const float* __restrict__ bv, float* __restrict__ out, int total)
{
    int i = blockIdx.x * 256 + threadIdx.x;
    if (i >= total) return;
    int l = i / 2304, j = i - l * 2304;
    float v = (j < 768) ? bq[l * 768 + j]
            : (j < 1536) ? bk[l * 768 + j - 768]
            : bv[l * 768 + j - 1536];
    out[i] = v;
}

__global__ __launch_bounds__(256) void embed_pe(
    const int* __restrict__ ids, const float* __restrict__ table,
    float* __restrict__ xf, u16* __restrict__ xb)
{
    const int idx = blockIdx.x * 256 + threadIdx.x;   // < 4096*768
    const int row = idx / 768, d = idx - row * 768;
    const int s = row & 2047;
    const float e = table[(long)ids[row] * 768 + d];
    const int j = d >> 1;
    // enc[s,2j]=sin(s/10000^(4j/768)), enc[s,2j+1]=cos(...)  (faithful to source)
    const float ang = (float)s * __expf(-0.011992630692677324f * (float)(4 * j));
    const float pe = (d & 1) ? cosf(ang) : sinf(ang);
    const float v = e + pe;
    xf[idx] = v;
    xb[idx] = f2bf(v);
}

// ---------------------------------------------------------------------------
extern "C" void kernel_launch(void* const* d_in, const int* in_sizes, int n_in,
                              void* d_out, int out_size, void* d_ws, size_t ws_size,
                              hipStream_t stream)
{
    const int S = 2048, D = 768, H = 12, L = 2, V = 32000, DF = 3072, M = 4096, NQKV = 2304;
    (void)in_sizes; (void)n_in; (void)out_size; (void)ws_size; (void)H; (void)S;

    const int*   ids  = (const int*)  d_in[0];
    const float* emb  = (const float*)d_in[1];
    const float* Wq   = (const float*)d_in[2];
    const float* bq   = (const float*)d_in[3];
    const float* Wk   = (const float*)d_in[4];
    const float* bk   = (const float*)d_in[5];
    const float* Wv   = (const float*)d_in[6];
    const float* bv   = (const float*)d_in[7];
    const float* Wo   = (const float*)d_in[8];
    const float* bo   = (const float*)d_in[9];
    const float* ln1g = (const float*)d_in[10];
    const float* ln1b = (const float*)d_in[11];
    const float* W1   = (const float*)d_in[12];
    const float* b1   = (const float*)d_in[13];
    const float* W2   = (const float*)d_in[14];
    const float* b2   = (const float*)d_in[15];
    const float* ln2g = (const float*)d_in[16];
    const float* ln2b = (const float*)d_in[17];
    const float* Wd   = (const float*)d_in[18];
    const float* bd   = (const float*)d_in[19];
    const float* lnmg = (const float*)d_in[20];
    const float* lnmb = (const float*)d_in[21];
    const float* decb = (const float*)d_in[22];

    char* p = (char*)d_ws;
    auto carve = [&](size_t bytes) { char* r = p; p += (bytes + 255) & ~(size_t)255; return r; };
    u16*   embB  = (u16*)  carve((size_t)V * D * 2);        // embed bf16 [V][D] (decoder Bt)
    u16*   wqkvT = (u16*)  carve((size_t)L * NQKV * D * 2); // fused qkv weights^T
    float* bqkv  = (float*)carve((size_t)L * NQKV * 4);
    u16*   woT   = (u16*)  carve((size_t)L * D * D * 2);
    u16*   w1T   = (u16*)  carve((size_t)L * DF * D * 2);
    u16*   w2T   = (u16*)  carve((size_t)L * D * DF * 2);
    u16*   wdT   = (u16*)  carve((size_t)D * D * 2);
    float* xf    = (float*)carve((size_t)M * D * 4);        // f32 residual stream
    u16*   xb    = (u16*)  carve((size_t)M * D * 2);
    u16*   qkvB  = (u16*)  carve((size_t)M * NQKV * 2);
    u16*   aoB   = (u16*)  carve((size_t)M * D * 2);        // attn out / head bf16
    float* tmpf  = (float*)carve((size_t)M * D * 4);
    u16*   hB    = (u16*)  carve((size_t)M * DF * 2);

    dim3 t32x8(32, 8);
    cvt_bf16_k<<<((long)V * D / 4 + 255) / 256, 256, 0, stream>>>(emb, embB, (long)V * D);
    for (int l = 0; l < L; ++l) {
        transpose_cvt<<<dim3(24, 24), t32x8, 0, stream>>>(Wq + (size_t)l * D * D, wqkvT + (size_t)l * NQKV * D,                    D, D);
        transpose_cvt<<<dim3(24, 24), t32x8, 0, stream>>>(Wk + (size_t)l * D * D, wqkvT + (size_t)l * NQKV * D + (size_t)D * D,    D, D);
        transpose_cvt<<<dim3(24, 24), t32x8, 0, stream>>>(Wv + (size_t)l * D * D, wqkvT + (size_t)l * NQKV * D + (size_t)2 * D * D, D, D);
        transpose_cvt<<<dim3(24, 24), t32x8, 0, stream>>>(Wo + (size_t)l * D * D, woT + (size_t)l * D * D, D, D);
        transpose_cvt<<<dim3(96, 24), t32x8, 0, stream>>>(W1 + (size_t)l * D * DF, w1T + (size_t)l * DF * D, D, DF);
        transpose_cvt<<<dim3(24, 96), t32x8, 0, stream>>>(W2 + (size_t)l * DF * D, w2T + (size_t)l * D * DF, DF, D);
    }
    transpose_cvt<<<dim3(24, 24), t32x8, 0, stream>>>(Wd, wdT, D, D);
    concat_bias<<<(L * NQKV + 255) / 256, 256, 0, stream>>>(bq, bk, bv, bqkv, L * NQKV);
    embed_pe<<<M * D / 256, 256, 0, stream>>>(ids, emb, xf, xb);

    const float scale = 0.036084391824351615f;  // 1/sqrt(768)  (source divides by sqrt(D))
    for (int l = 0; l < L; ++l) {
        gemm_bf16<0, 0><<<dim3(NQKV / 128, M / 128), 256, 0, stream>>>(xb, wqkvT + (size_t)l * NQKV * D, bqkv + l * NQKV, qkvB, NQKV, D);
        attn_fwd<<<dim3(24, 16), 256, 0, stream>>>(qkvB, aoB, scale);
        gemm_bf16<0, 1><<<dim3(D / 128, M / 128), 256, 0, stream>>>(aoB, woT + (size_t)l * D * D, bo + l * D, tmpf, D, D);
        ln_fused<<<M, 256, 0, stream>>>(xf, tmpf, ln1g + l * D, ln1b + l * D, xf, xb);
        gemm_bf16<1, 0><<<dim3(DF / 128, M / 128), 256, 0, stream>>>(xb, w1T + (size_t)l * DF * D, b1 + l * DF, hB, DF, D);
        gemm_bf16<0, 1><<<dim3(D / 128, M / 128), 256, 0, stream>>>(hB, w2T + (size_t)l * D * DF, b2 + l * D, tmpf, D, DF);
        ln_fused<<<M, 256, 0, stream>>>(xf, tmpf, ln2g + l * D, ln2b + l * D, xf, xb);
    }
    // MLM head
    gemm_bf16<1, 1><<<dim3(D / 128, M / 128), 256, 0, stream>>>(xb, wdT, bd, tmpf, D, D);
    ln_fused<<<M, 256, 0, stream>>>(tmpf, nullptr, lnmg, lnmb, nullptr, aoB);
    gemm_bf16<0, 1><<<dim3(V / 128, M / 128), 256, 0, stream>>>(aoB, embB, decb, (float*)d_out, V, D);
}